// Round 3
// baseline (425.521 us; speedup 1.0000x reference)
//
#include <hip/hip_runtime.h>

#define Nn 100000
#define Ee 600000
#define Fin 128
#define Hd  256
#define NB  ((Nn + 1023) / 1024)   // 98 scan blocks

typedef __attribute__((ext_vector_type(8))) short short8;
typedef __attribute__((ext_vector_type(4))) float floatx4;

__device__ __forceinline__ float bf2f(unsigned short h) {
    return __uint_as_float(((unsigned int)h) << 16);
}
__device__ __forceinline__ unsigned short f2bf(float f) {
    unsigned int u = __float_as_uint(f);
    u += 0x7FFFu + ((u >> 16) & 1u);   // round-to-nearest-even
    return (unsigned short)(u >> 16);
}
__device__ __forceinline__ float loadf(const void* p, int i, int f32) {
    return f32 ? ((const float*)p)[i] : bf2f(((const unsigned short*)p)[i]);
}
__device__ __forceinline__ void gload_lds16(const void* g, void* lds) {
    __builtin_amdgcn_global_load_lds((const __attribute__((address_space(1))) void*)g,
                                     (__attribute__((address_space(3))) void*)lds,
                                     16, 0, 0);
}

// ---- runtime probes: flag[0] = edge_index is int64, flag[1] = floats are f32 ----
__global__ void k_detect(const unsigned int* __restrict__ ei,
                         const unsigned short* __restrict__ xu,
                         int* __restrict__ flag) {
    if (blockIdx.x == 0 && threadIdx.x == 0) {
        int is64 = 1;
        for (int i = 1; i < 64; i += 2)
            if (ei[i] != 0u) { is64 = 0; break; }
        flag[0] = is64;
        int isf32 = 0;
        for (int i = 0; i < 512; i += 2) {
            unsigned e = (xu[i] >> 7) & 0xFFu;
            if (e >= 0xC0u) { isf32 = 1; break; }
        }
        flag[1] = isf32;
    }
}

__device__ __forceinline__ void get_edge(const int* __restrict__ ei, int is64, int e,
                                         int& s, int& d) {
    if (is64) { s = ei[2 * e]; d = ei[2 * (Ee + e)]; }
    else      { s = ei[e];     d = ei[Ee + e]; }
}

__global__ void k_zero(int* __restrict__ p, int n) {
    int i = blockIdx.x * 256 + threadIdx.x;
    if (i < n) p[i] = 0;
}

// ---- x -> xb (bf16 internal) ----
__global__ void k_convert(const void* __restrict__ x, unsigned short* __restrict__ xb,
                          const int* __restrict__ flag) {
    int i = (blockIdx.x * 256 + threadIdx.x) * 4;
    if (i >= Nn * Fin) return;
    if (flag[1]) {
        float4 v = ((const float4*)x)[i >> 2];
        ushort4 u;
        u.x = f2bf(v.x); u.y = f2bf(v.y); u.z = f2bf(v.z); u.w = f2bf(v.w);
        ((ushort4*)xb)[i >> 2] = u;
    } else {
        ((ushort4*)xb)[i >> 2] = ((const ushort4*)x)[i >> 2];
    }
}

// ---- weight pre-transpose: Wt[n][k] bf16, concat [Wl;Wr] along k ----
__global__ void k_prep(const void* __restrict__ Wl1, const void* __restrict__ Wr1,
                       const void* __restrict__ Wl2, const void* __restrict__ Wr2,
                       unsigned short* __restrict__ Wt1, unsigned short* __restrict__ Wt2,
                       const int* __restrict__ flag) {
    int f32 = flag[1];
    int tid = blockIdx.x * 256 + threadIdx.x;
    if (tid < 256 * 256) {
        int n = tid >> 8, k = tid & 255;
        float v = (k < 128) ? loadf(Wl1, k * 256 + n, f32) : loadf(Wr1, (k - 128) * 256 + n, f32);
        Wt1[n * 256 + k] = f2bf(v);
    }
    int t2 = tid - 256 * 256;
    if (t2 >= 0 && t2 < 256 * 512) {
        int n = t2 >> 9, k = t2 & 511;
        float v = (k < 256) ? loadf(Wl2, k * 256 + n, f32) : loadf(Wr2, (k - 256) * 256 + n, f32);
        Wt2[n * 512 + k] = f2bf(v);
    }
}

// ---- CSR build ----
__global__ void k_count(const int* __restrict__ ei, const int* __restrict__ flag,
                        int* __restrict__ cnt) {
    int e = blockIdx.x * 256 + threadIdx.x;
    if (e >= Ee) return;
    int is64 = flag[0], s, d;
    get_edge(ei, is64, e, s, d);
    atomicAdd(&cnt[d], 1);
}

// hierarchical scan: k_bsum -> k_bscan -> k_rowptr (all coalesced int4)
__global__ void k_bsum(const int* __restrict__ cnt, int* __restrict__ bsum) {
    __shared__ int red[256];
    int b = blockIdx.x, t = threadIdx.x;
    int i = b * 1024 + t * 4;
    int s = 0;
    if (i + 3 < Nn) {
        int4 v = *reinterpret_cast<const int4*>(cnt + i);
        s = v.x + v.y + v.z + v.w;
    } else {
        for (int j = 0; j < 4; j++) if (i + j < Nn) s += cnt[i + j];
    }
    red[t] = s;
    __syncthreads();
    for (int off = 128; off > 0; off >>= 1) {
        if (t < off) red[t] += red[t + off];
        __syncthreads();
    }
    if (t == 0) bsum[b] = red[0];
}

__global__ void k_bscan(const int* __restrict__ bsum, int* __restrict__ bpre,
                        int* __restrict__ rowptr) {
    __shared__ int sc[128];
    int t = threadIdx.x;
    int v = (t < NB) ? bsum[t] : 0;
    sc[t] = v;
    __syncthreads();
    for (int off = 1; off < 128; off <<= 1) {
        int add = (t >= off) ? sc[t - off] : 0;
        __syncthreads();
        sc[t] += add;
        __syncthreads();
    }
    if (t < NB) bpre[t] = sc[t] - v;          // exclusive prefix
    if (t == 127) rowptr[Nn] = sc[127];       // grand total (== Ee)
}

__global__ void k_rowptr(const int* __restrict__ cnt, const int* __restrict__ bpre,
                         int* __restrict__ rowptr) {
    __shared__ int sc[256];
    int b = blockIdx.x, t = threadIdx.x;
    int i = b * 1024 + t * 4;
    int4 c = make_int4(0, 0, 0, 0);
    if (i + 3 < Nn) {
        c = *reinterpret_cast<const int4*>(cnt + i);
    } else {
        if (i     < Nn) c.x = cnt[i];
        if (i + 1 < Nn) c.y = cnt[i + 1];
        if (i + 2 < Nn) c.z = cnt[i + 2];
        if (i + 3 < Nn) c.w = cnt[i + 3];
    }
    int s = c.x + c.y + c.z + c.w;
    sc[t] = s;
    __syncthreads();
    for (int off = 1; off < 256; off <<= 1) {
        int add = (t >= off) ? sc[t - off] : 0;
        __syncthreads();
        sc[t] += add;
        __syncthreads();
    }
    int p = bpre[b] + sc[t] - s;   // exclusive prefix of element i
    int4 r;
    r.x = p;
    r.y = r.x + c.x;
    r.z = r.y + c.y;
    r.w = r.z + c.z;
    if (i + 3 < Nn) {
        *reinterpret_cast<int4*>(rowptr + i) = r;
    } else {
        if (i     < Nn) rowptr[i]     = r.x;
        if (i + 1 < Nn) rowptr[i + 1] = r.y;
        if (i + 2 < Nn) rowptr[i + 2] = r.z;
        if (i + 3 < Nn) rowptr[i + 3] = r.w;
    }
}

__global__ void k_fill(const int* __restrict__ ei, const int* __restrict__ flag,
                       const int* __restrict__ rowptr, int* __restrict__ cur,
                       int* __restrict__ srcl) {
    int e = blockIdx.x * 256 + threadIdx.x;
    if (e >= Ee) return;
    int is64 = flag[0], s, d;
    get_edge(ei, is64, e, s, d);
    int pos = atomicAdd(&cur[d], 1);
    srcl[rowptr[d] + pos] = s;
}

// ---- gather-based mean aggregation: one wave per node, 4-deep MLP ----
template <int F, int SIN, int SOUT>
__device__ __forceinline__ void agg_body(const unsigned short* __restrict__ X,
                                         unsigned short* __restrict__ O,
                                         const int* __restrict__ rowptr,
                                         const int* __restrict__ srcl) {
    int gw = (blockIdx.x * blockDim.x + threadIdx.x) >> 6;
    int lane = threadIdx.x & 63;
    if (gw >= Nn) return;
    int b = rowptr[gw], e = rowptr[gw + 1];
    constexpr int C = F / 64;
    float acc[C] = {};
    if (e > b) {
        int last = e - 1;
        for (int i = b; i < e; i += 4) {
            int sv[4];
            float w[4];
#pragma unroll
            for (int j = 0; j < 4; j++) {
                int id = i + j;
                sv[j] = srcl[id < last ? id : last];
                w[j] = (id < e) ? 1.f : 0.f;
            }
            if constexpr (C == 2) {
                ushort2 u[4];
#pragma unroll
                for (int j = 0; j < 4; j++)
                    u[j] = *reinterpret_cast<const ushort2*>(X + (size_t)sv[j] * SIN + lane * 2);
#pragma unroll
                for (int j = 0; j < 4; j++) {
                    acc[0] = fmaf(w[j], bf2f(u[j].x), acc[0]);
                    acc[1] = fmaf(w[j], bf2f(u[j].y), acc[1]);
                }
            } else {
                ushort4 u[4];
#pragma unroll
                for (int j = 0; j < 4; j++)
                    u[j] = *reinterpret_cast<const ushort4*>(X + (size_t)sv[j] * SIN + lane * 4);
#pragma unroll
                for (int j = 0; j < 4; j++) {
                    acc[0] = fmaf(w[j], bf2f(u[j].x), acc[0]);
                    acc[1] = fmaf(w[j], bf2f(u[j].y), acc[1]);
                    acc[2] = fmaf(w[j], bf2f(u[j].z), acc[2]);
                    acc[3] = fmaf(w[j], bf2f(u[j].w), acc[3]);
                }
            }
        }
    }
    float inv = 1.f / (float)max(e - b, 1);
    unsigned short* op = O + (size_t)gw * SOUT + lane * C;
    if constexpr (C == 2) {
        ushort2 u; u.x = f2bf(acc[0] * inv); u.y = f2bf(acc[1] * inv);
        *reinterpret_cast<ushort2*>(op) = u;
    } else {
        ushort4 u;
        u.x = f2bf(acc[0] * inv); u.y = f2bf(acc[1] * inv);
        u.z = f2bf(acc[2] * inv); u.w = f2bf(acc[3] * inv);
        *reinterpret_cast<ushort4*>(op) = u;
    }
}

__global__ void k_agg1(const unsigned short* __restrict__ xb, unsigned short* __restrict__ agg1,
                       const int* __restrict__ rowptr, const int* __restrict__ srcl) {
    agg_body<Fin, Fin, Fin>(xb, agg1, rowptr, srcl);
}

__global__ void k_agg2(const int* __restrict__ rowptr, const int* __restrict__ srcl,
                       unsigned short* __restrict__ acat_ws) {
    agg_body<Hd, 512, 512>(acat_ws + 256, acat_ws, rowptr, srcl);
}

// ---- MFMA GEMM core: double-buffered LDS (BK=32) + counted vmcnt pipeline ----
// Per tile: stage next (3 gload_lds/thread) -> vmcnt(3) (next tile stays in
// flight across MFMA) -> barrier -> ds_read+MFMA -> lgkmcnt(0)+barrier.
// LDS total unchanged at 48 KB (2 x (8KB A + 16KB B)) -> 3 blocks/CU preserved.
// XOR chunk swizzle for 64B rows: chunk = cs ^ ((row>>1)&3); read side mirrors.
// Bank aliasing: (row&1, chunk) spans 8 slots over 16 lanes -> 2-way = free.
template <int KT, int K1, int S1, int S2>
__device__ __forceinline__ void gemm_core_pipe(const unsigned short* __restrict__ A1,
                                               const unsigned short* __restrict__ A2,
                                               const unsigned short* __restrict__ Wt,
                                               floatx4 (&acc)[4][4],
                                               unsigned short* sA, unsigned short* sB,
                                               int m_base) {
    const int tid = threadIdx.x;
    const int lane = tid & 63, wid = tid >> 6;
    const int wm = wid & 1, wn = wid >> 1;
    const int quad = lane >> 4, l16 = lane & 15;
    const int rs = tid >> 2, cs = tid & 3;
    constexpr int NT = KT / 32;

#define STAGE(t, buf)                                                              \
    {                                                                              \
        int kb_ = (t) * 32;                                                        \
        {                                                                          \
            int r_ = rs;                                                           \
            int gk_ = kb_ + ((cs ^ ((r_ >> 1) & 3)) << 3);                         \
            int m_ = m_base + r_; if (m_ >= Nn) m_ = Nn - 1;                       \
            const unsigned short* gp_ = (gk_ < K1)                                 \
                ? A1 + (size_t)m_ * S1 + gk_                                       \
                : A2 + (size_t)m_ * S2 + (gk_ - K1);                               \
            gload_lds16(gp_, sA + (buf) * 4096 + wid * 512);                       \
        }                                                                          \
        _Pragma("unroll")                                                          \
        for (int i_ = 0; i_ < 2; i_++) {                                           \
            int n_ = i_ * 128 + rs;                                                \
            int gk_ = kb_ + ((cs ^ ((n_ >> 1) & 3)) << 3);                         \
            gload_lds16(Wt + (size_t)n_ * KT + gk_,                                \
                        sB + (buf) * 8192 + i_ * 4096 + wid * 512);                \
        }                                                                          \
    }

#define COMPUTE(buf)                                                               \
    {                                                                              \
        short8 a_[4], b_[4];                                                       \
        _Pragma("unroll")                                                          \
        for (int mt_ = 0; mt_ < 4; mt_++) {                                        \
            int r_ = wm * 64 + mt_ * 16 + l16;                                     \
            a_[mt_] = *reinterpret_cast<const short8*>(                            \
                sA + (buf) * 4096 + r_ * 32 + ((quad ^ ((r_ >> 1) & 3)) << 3));    \
        }                                                                          \
        _Pragma("unroll")                                                          \
        for (int nt_ = 0; nt_ < 4; nt_++) {                                        \
            int n_ = wn * 64 + nt_ * 16 + l16;                                     \
            b_[nt_] = *reinterpret_cast<const short8*>(                            \
                sB + (buf) * 8192 + n_ * 32 + ((quad ^ ((n_ >> 1) & 3)) << 3));    \
        }                                                                          \
        _Pragma("unroll")                                                          \
        for (int mt_ = 0; mt_ < 4; mt_++)                                          \
            _Pragma("unroll")                                                      \
            for (int nt_ = 0; nt_ < 4; nt_++)                                      \
                acc[mt_][nt_] = __builtin_amdgcn_mfma_f32_16x16x32_bf16(           \
                    a_[mt_], b_[nt_], acc[mt_][nt_], 0, 0, 0);                     \
    }

    STAGE(0, 0)
#pragma unroll
    for (int t = 0; t < NT - 1; t++) {
        STAGE(t + 1, (t + 1) & 1)
        asm volatile("s_waitcnt vmcnt(3)" ::: "memory");   // current tile landed; next stays in flight
        __builtin_amdgcn_sched_barrier(0);
        __builtin_amdgcn_s_barrier();
        __builtin_amdgcn_sched_barrier(0);
        COMPUTE(t & 1)
        __builtin_amdgcn_sched_barrier(0);
        asm volatile("s_waitcnt lgkmcnt(0)" ::: "memory"); // my ds_reads done before buffer reuse
        __builtin_amdgcn_s_barrier();
        __builtin_amdgcn_sched_barrier(0);
    }
    asm volatile("s_waitcnt vmcnt(0)" ::: "memory");
    __builtin_amdgcn_sched_barrier(0);
    __builtin_amdgcn_s_barrier();
    __builtin_amdgcn_sched_barrier(0);
    COMPUTE((NT - 1) & 1)
#undef STAGE
#undef COMPUTE
}

// layer 1: h = relu([agg1|xb] @ Wt1 + b1) -> Acat[:,256:512) (bf16)
__global__ __launch_bounds__(512) void k_gemm1(const unsigned short* __restrict__ agg1,
                                               const unsigned short* __restrict__ xb,
                                               const unsigned short* __restrict__ Wt1,
                                               const void* __restrict__ bias,
                                               const int* __restrict__ flag,
                                               unsigned short* __restrict__ acat_ws) {
    __shared__ unsigned short sA[8192];    // 2 x 4096
    __shared__ unsigned short sB[16384];   // 2 x 8192
    int f32 = flag[1];
    int wid = threadIdx.x >> 6, lane = threadIdx.x & 63;
    int wm = wid & 1, wn = wid >> 1;
    int quad = lane >> 4, l16 = lane & 15;
    int m_base = blockIdx.x * 128;
    floatx4 acc[4][4] = {};
    gemm_core_pipe<256, 128, 128, 128>(agg1, xb, Wt1, acc, sA, sB, m_base);
#pragma unroll
    for (int nt = 0; nt < 4; nt++) {
        int n = wn * 64 + nt * 16 + l16;
        float bv = loadf(bias, n, f32);
#pragma unroll
        for (int mt = 0; mt < 4; mt++) {
#pragma unroll
            for (int r = 0; r < 4; r++) {
                int m = m_base + wm * 64 + mt * 16 + quad * 4 + r;
                if (m < Nn) {
                    float v = acc[mt][nt][r] + bv;
                    v = v > 0.f ? v : 0.f;
                    acat_ws[(size_t)m * 512 + 256 + n] = f2bf(v);
                }
            }
        }
    }
}

// layer 2: out = [agg2|h] @ Wt2 + b2
__global__ __launch_bounds__(512) void k_gemm2(const unsigned short* __restrict__ Wt2,
                                               const void* __restrict__ bias,
                                               const int* __restrict__ flag,
                                               const unsigned short* __restrict__ acat_ws,
                                               void* __restrict__ out) {
    __shared__ unsigned short sA[8192];
    __shared__ unsigned short sB[16384];
    int f32 = flag[1];
    int wid = threadIdx.x >> 6, lane = threadIdx.x & 63;
    int wm = wid & 1, wn = wid >> 1;
    int quad = lane >> 4, l16 = lane & 15;
    int m_base = blockIdx.x * 128;
    floatx4 acc[4][4] = {};
    gemm_core_pipe<512, 256, 512, 512>(acat_ws, acat_ws + 256, Wt2, acc, sA, sB, m_base);
#pragma unroll
    for (int nt = 0; nt < 4; nt++) {
        int n = wn * 64 + nt * 16 + l16;
        float bv = loadf(bias, n, f32);
#pragma unroll
        for (int mt = 0; mt < 4; mt++) {
#pragma unroll
            for (int r = 0; r < 4; r++) {
                int m = m_base + wm * 64 + mt * 16 + quad * 4 + r;
                if (m < Nn) {
                    float v = acc[mt][nt][r] + bv;
                    if (f32) ((float*)out)[(size_t)m * Hd + n] = v;
                    else     ((unsigned short*)out)[(size_t)m * Hd + n] = f2bf(v);
                }
            }
        }
    }
}

extern "C" void kernel_launch(void* const* d_in, const int* in_sizes, int n_in,
                              void* d_out, int out_size, void* d_ws, size_t ws_size,
                              hipStream_t stream) {
    const void* x   = d_in[0];
    const int*  ei  = (const int*)d_in[1];
    const void* Wl1 = d_in[2];
    const void* Wr1 = d_in[3];
    const void* b1  = d_in[4];
    const void* Wl2 = d_in[5];
    const void* Wr2 = d_in[6];
    const void* b2  = d_in[7];

    char* ws = (char*)d_ws;
    size_t off_cnt    = 0;
    size_t off_cur    = off_cnt + (size_t)Nn * 4;
    size_t off_rowptr = off_cur + (size_t)Nn * 4;
    size_t off_srcl   = off_rowptr + (size_t)(Nn + 4) * 4;
    size_t off_flag   = off_srcl + (size_t)Ee * 4;
    size_t off_bsum   = ((off_flag + 8 + 255) / 256) * 256;   // NB ints
    size_t off_bpre   = off_bsum + 128 * 4;                   // NB ints
    size_t off_wt1    = off_bpre + 128 * 4;
    size_t off_wt2    = off_wt1 + 256 * 256 * 2;
    size_t off_xb     = off_wt2 + 256 * 512 * 2;
    size_t off_agg1   = off_xb + (size_t)Nn * Fin * 2;
    size_t off_acat   = off_agg1 + (size_t)Nn * Fin * 2;

    int*            cnt     = (int*)(ws + off_cnt);
    int*            cur     = (int*)(ws + off_cur);
    int*            rowptr  = (int*)(ws + off_rowptr);
    int*            srcl    = (int*)(ws + off_srcl);
    int*            flag    = (int*)(ws + off_flag);
    int*            bsum    = (int*)(ws + off_bsum);
    int*            bpre    = (int*)(ws + off_bpre);
    unsigned short* Wt1     = (unsigned short*)(ws + off_wt1);
    unsigned short* Wt2     = (unsigned short*)(ws + off_wt2);
    unsigned short* xb      = (unsigned short*)(ws + off_xb);
    unsigned short* agg1    = (unsigned short*)(ws + off_agg1);
    unsigned short* acat_ws = (unsigned short*)(ws + off_acat);

    k_detect<<<1, 64, 0, stream>>>((const unsigned int*)ei, (const unsigned short*)x, flag);
    k_zero<<<(2 * Nn + 255) / 256, 256, 0, stream>>>(cnt, 2 * Nn);
    k_convert<<<(Nn * Fin / 4 + 255) / 256, 256, 0, stream>>>(x, xb, flag);
    k_prep<<<768, 256, 0, stream>>>(Wl1, Wr1, Wl2, Wr2, Wt1, Wt2, flag);

    int eb = (Ee + 255) / 256;
    k_count<<<eb, 256, 0, stream>>>(ei, flag, cnt);
    k_bsum<<<NB, 256, 0, stream>>>(cnt, bsum);
    k_bscan<<<1, 128, 0, stream>>>(bsum, bpre, rowptr);
    k_rowptr<<<NB, 256, 0, stream>>>(cnt, bpre, rowptr);
    k_fill<<<eb, 256, 0, stream>>>(ei, flag, rowptr, cur, srcl);

    int ab = (Nn * 64 + 255) / 256;
    int gx = (Nn + 127) / 128;

    k_agg1<<<ab, 256, 0, stream>>>(xb, agg1, rowptr, srcl);
    k_gemm1<<<gx, 512, 0, stream>>>(agg1, xb, Wt1, b1, flag, acat_ws);
    k_agg2<<<ab, 256, 0, stream>>>(rowptr, srcl, acat_ws);
    k_gemm2<<<gx, 512, 0, stream>>>(Wt2, b2, flag, acat_ws, d_out);
}

// Round 4
// 422.566 us; speedup vs baseline: 1.0070x; 1.0070x over previous
//
#include <hip/hip_runtime.h>

#define Nn 100000
#define Ee 600000
#define Fin 128
#define Hd  256
#define NB  ((Nn + 1023) / 1024)   // 98 scan blocks

typedef __attribute__((ext_vector_type(8))) short short8;
typedef __attribute__((ext_vector_type(4))) float floatx4;

__device__ __forceinline__ float bf2f(unsigned short h) {
    return __uint_as_float(((unsigned int)h) << 16);
}
__device__ __forceinline__ unsigned short f2bf(float f) {
    unsigned int u = __float_as_uint(f);
    u += 0x7FFFu + ((u >> 16) & 1u);   // round-to-nearest-even
    return (unsigned short)(u >> 16);
}
__device__ __forceinline__ float loadf(const void* p, int i, int f32) {
    return f32 ? ((const float*)p)[i] : bf2f(((const unsigned short*)p)[i]);
}
__device__ __forceinline__ void gload_lds16(const void* g, void* lds) {
    __builtin_amdgcn_global_load_lds((const __attribute__((address_space(1))) void*)g,
                                     (__attribute__((address_space(3))) void*)lds,
                                     16, 0, 0);
}

// ---- runtime probes: flag[0] = edge_index is int64, flag[1] = floats are f32 ----
__global__ void k_detect(const unsigned int* __restrict__ ei,
                         const unsigned short* __restrict__ xu,
                         int* __restrict__ flag) {
    if (blockIdx.x == 0 && threadIdx.x == 0) {
        int is64 = 1;
        for (int i = 1; i < 64; i += 2)
            if (ei[i] != 0u) { is64 = 0; break; }
        flag[0] = is64;
        int isf32 = 0;
        for (int i = 0; i < 512; i += 2) {
            unsigned e = (xu[i] >> 7) & 0xFFu;
            if (e >= 0xC0u) { isf32 = 1; break; }
        }
        flag[1] = isf32;
    }
}

__device__ __forceinline__ void get_edge(const int* __restrict__ ei, int is64, int e,
                                         int& s, int& d) {
    if (is64) { s = ei[2 * e]; d = ei[2 * (Ee + e)]; }
    else      { s = ei[e];     d = ei[Ee + e]; }
}

__global__ void k_zero(int* __restrict__ p, int n) {
    int i = blockIdx.x * 256 + threadIdx.x;
    if (i < n) p[i] = 0;
}

// ---- x -> xb (bf16 internal) ----
__global__ void k_convert(const void* __restrict__ x, unsigned short* __restrict__ xb,
                          const int* __restrict__ flag) {
    int i = (blockIdx.x * 256 + threadIdx.x) * 4;
    if (i >= Nn * Fin) return;
    if (flag[1]) {
        float4 v = ((const float4*)x)[i >> 2];
        ushort4 u;
        u.x = f2bf(v.x); u.y = f2bf(v.y); u.z = f2bf(v.z); u.w = f2bf(v.w);
        ((ushort4*)xb)[i >> 2] = u;
    } else {
        ((ushort4*)xb)[i >> 2] = ((const ushort4*)x)[i >> 2];
    }
}

// ---- weight pre-transpose: Wt[n][k] bf16, concat [Wl;Wr] along k ----
__global__ void k_prep(const void* __restrict__ Wl1, const void* __restrict__ Wr1,
                       const void* __restrict__ Wl2, const void* __restrict__ Wr2,
                       unsigned short* __restrict__ Wt1, unsigned short* __restrict__ Wt2,
                       const int* __restrict__ flag) {
    int f32 = flag[1];
    int tid = blockIdx.x * 256 + threadIdx.x;
    if (tid < 256 * 256) {
        int n = tid >> 8, k = tid & 255;
        float v = (k < 128) ? loadf(Wl1, k * 256 + n, f32) : loadf(Wr1, (k - 128) * 256 + n, f32);
        Wt1[n * 256 + k] = f2bf(v);
    }
    int t2 = tid - 256 * 256;
    if (t2 >= 0 && t2 < 256 * 512) {
        int n = t2 >> 9, k = t2 & 511;
        float v = (k < 256) ? loadf(Wl2, k * 256 + n, f32) : loadf(Wr2, (k - 256) * 256 + n, f32);
        Wt2[n * 512 + k] = f2bf(v);
    }
}

// ---- CSR build ----
__global__ void k_count(const int* __restrict__ ei, const int* __restrict__ flag,
                        int* __restrict__ cnt) {
    int e = blockIdx.x * 256 + threadIdx.x;
    if (e >= Ee) return;
    int is64 = flag[0], s, d;
    get_edge(ei, is64, e, s, d);
    atomicAdd(&cnt[d], 1);
}

// hierarchical scan: k_bsum -> k_bscan -> k_rowptr (all coalesced int4)
__global__ void k_bsum(const int* __restrict__ cnt, int* __restrict__ bsum) {
    __shared__ int red[256];
    int b = blockIdx.x, t = threadIdx.x;
    int i = b * 1024 + t * 4;
    int s = 0;
    if (i + 3 < Nn) {
        int4 v = *reinterpret_cast<const int4*>(cnt + i);
        s = v.x + v.y + v.z + v.w;
    } else {
        for (int j = 0; j < 4; j++) if (i + j < Nn) s += cnt[i + j];
    }
    red[t] = s;
    __syncthreads();
    for (int off = 128; off > 0; off >>= 1) {
        if (t < off) red[t] += red[t + off];
        __syncthreads();
    }
    if (t == 0) bsum[b] = red[0];
}

__global__ void k_bscan(const int* __restrict__ bsum, int* __restrict__ bpre,
                        int* __restrict__ rowptr) {
    __shared__ int sc[128];
    int t = threadIdx.x;
    int v = (t < NB) ? bsum[t] : 0;
    sc[t] = v;
    __syncthreads();
    for (int off = 1; off < 128; off <<= 1) {
        int add = (t >= off) ? sc[t - off] : 0;
        __syncthreads();
        sc[t] += add;
        __syncthreads();
    }
    if (t < NB) bpre[t] = sc[t] - v;          // exclusive prefix
    if (t == 127) rowptr[Nn] = sc[127];       // grand total (== Ee)
}

__global__ void k_rowptr(const int* __restrict__ cnt, const int* __restrict__ bpre,
                         int* __restrict__ rowptr) {
    __shared__ int sc[256];
    int b = blockIdx.x, t = threadIdx.x;
    int i = b * 1024 + t * 4;
    int4 c = make_int4(0, 0, 0, 0);
    if (i + 3 < Nn) {
        c = *reinterpret_cast<const int4*>(cnt + i);
    } else {
        if (i     < Nn) c.x = cnt[i];
        if (i + 1 < Nn) c.y = cnt[i + 1];
        if (i + 2 < Nn) c.z = cnt[i + 2];
        if (i + 3 < Nn) c.w = cnt[i + 3];
    }
    int s = c.x + c.y + c.z + c.w;
    sc[t] = s;
    __syncthreads();
    for (int off = 1; off < 256; off <<= 1) {
        int add = (t >= off) ? sc[t - off] : 0;
        __syncthreads();
        sc[t] += add;
        __syncthreads();
    }
    int p = bpre[b] + sc[t] - s;   // exclusive prefix of element i
    int4 r;
    r.x = p;
    r.y = r.x + c.x;
    r.z = r.y + c.y;
    r.w = r.z + c.z;
    if (i + 3 < Nn) {
        *reinterpret_cast<int4*>(rowptr + i) = r;
    } else {
        if (i     < Nn) rowptr[i]     = r.x;
        if (i + 1 < Nn) rowptr[i + 1] = r.y;
        if (i + 2 < Nn) rowptr[i + 2] = r.z;
        if (i + 3 < Nn) rowptr[i + 3] = r.w;
    }
}

__global__ void k_fill(const int* __restrict__ ei, const int* __restrict__ flag,
                       const int* __restrict__ rowptr, int* __restrict__ cur,
                       int* __restrict__ srcl) {
    int e = blockIdx.x * 256 + threadIdx.x;
    if (e >= Ee) return;
    int is64 = flag[0], s, d;
    get_edge(ei, is64, e, s, d);
    int pos = atomicAdd(&cur[d], 1);
    srcl[rowptr[d] + pos] = s;
}

// ---- gather-based mean aggregation: one wave per node, 8-deep MLP ----
// Poisson(6) degrees: stride-8 cuts the serial gather-block chain from
// E[ceil(deg/4)]=1.9 to E[ceil(deg/8)]=1.15. Clamped slots re-load the `last`
// row (L2 hit, weight 0.0 -> exact). Masked terms are *0.0 (exact).
template <int F, int SIN, int SOUT>
__device__ __forceinline__ void agg_body(const unsigned short* __restrict__ X,
                                         unsigned short* __restrict__ O,
                                         const int* __restrict__ rowptr,
                                         const int* __restrict__ srcl) {
    int gw = (blockIdx.x * blockDim.x + threadIdx.x) >> 6;
    int lane = threadIdx.x & 63;
    if (gw >= Nn) return;
    int b = rowptr[gw], e = rowptr[gw + 1];
    constexpr int C = F / 64;
    float acc[C] = {};
    if (e > b) {
        int last = e - 1;
        for (int i = b; i < e; i += 8) {
            int sv[8];
            float w[8];
#pragma unroll
            for (int j = 0; j < 8; j++) {
                int id = i + j;
                sv[j] = srcl[id < last ? id : last];
                w[j] = (id < e) ? 1.f : 0.f;
            }
            if constexpr (C == 2) {
                ushort2 u[8];
#pragma unroll
                for (int j = 0; j < 8; j++)
                    u[j] = *reinterpret_cast<const ushort2*>(X + (size_t)sv[j] * SIN + lane * 2);
#pragma unroll
                for (int j = 0; j < 8; j++) {
                    acc[0] = fmaf(w[j], bf2f(u[j].x), acc[0]);
                    acc[1] = fmaf(w[j], bf2f(u[j].y), acc[1]);
                }
            } else {
                ushort4 u[8];
#pragma unroll
                for (int j = 0; j < 8; j++)
                    u[j] = *reinterpret_cast<const ushort4*>(X + (size_t)sv[j] * SIN + lane * 4);
#pragma unroll
                for (int j = 0; j < 8; j++) {
                    acc[0] = fmaf(w[j], bf2f(u[j].x), acc[0]);
                    acc[1] = fmaf(w[j], bf2f(u[j].y), acc[1]);
                    acc[2] = fmaf(w[j], bf2f(u[j].z), acc[2]);
                    acc[3] = fmaf(w[j], bf2f(u[j].w), acc[3]);
                }
            }
        }
    }
    float inv = 1.f / (float)max(e - b, 1);
    unsigned short* op = O + (size_t)gw * SOUT + lane * C;
    if constexpr (C == 2) {
        ushort2 u; u.x = f2bf(acc[0] * inv); u.y = f2bf(acc[1] * inv);
        *reinterpret_cast<ushort2*>(op) = u;
    } else {
        ushort4 u;
        u.x = f2bf(acc[0] * inv); u.y = f2bf(acc[1] * inv);
        u.z = f2bf(acc[2] * inv); u.w = f2bf(acc[3] * inv);
        *reinterpret_cast<ushort4*>(op) = u;
    }
}

__global__ void k_agg1(const unsigned short* __restrict__ xb, unsigned short* __restrict__ agg1,
                       const int* __restrict__ rowptr, const int* __restrict__ srcl) {
    agg_body<Fin, Fin, Fin>(xb, agg1, rowptr, srcl);
}

__global__ void k_agg2(const int* __restrict__ rowptr, const int* __restrict__ srcl,
                       unsigned short* __restrict__ acat_ws) {
    agg_body<Hd, 512, 512>(acat_ws + 256, acat_ws, rowptr, srcl);
}

// ---- MFMA GEMM core (Round-2 structure, reverted): async LDS staging of BOTH
// A and B, BK=64, single-buffered, 2 barriers per kb. The BK=32 dbuf+vmcnt
// pipeline (R3) regressed — matches learn_hip m99/m131: implicit 3-blocks/CU
// wave overlap already covers the drain; extra barriers cost more.
template <int KT, int K1, int S1, int S2>
__device__ __forceinline__ void gemm_core_lds(const unsigned short* __restrict__ A1,
                                              const unsigned short* __restrict__ A2,
                                              const unsigned short* __restrict__ Wt,
                                              floatx4 (&acc)[4][4],
                                              unsigned short* sA, unsigned short* sB,
                                              int m_base) {
    const int tid = threadIdx.x;
    const int lane = tid & 63, wid = tid >> 6;
    const int wm = wid & 1, wn = wid >> 1;
    const int quad = lane >> 4, l16 = lane & 15;
    const int n_base = wn * 64;
    const int rs = tid >> 3;       // row-octet owner: 64 rows per 512-thread pass
    const int cs = tid & 7;        // k-chunk slot (8 shorts each)

    for (int kb = 0; kb < KT; kb += 64) {
        __syncthreads();
        // stage A: 128 rows x 64 k, pre-swizzled global source -> linear LDS dest
#pragma unroll
        for (int i = 0; i < 2; i++) {
            int r = i * 64 + rs;
            int gk = kb + ((cs ^ (r & 7)) << 3);
            int m = m_base + r; if (m >= Nn) m = Nn - 1;
            const unsigned short* gp = (gk < K1)
                ? A1 + (size_t)m * S1 + gk
                : A2 + (size_t)m * S2 + (gk - K1);
            gload_lds16(gp, sA + i * 4096 + wid * 512);
        }
        // stage B: 256 rows x 64 k, same swizzle scheme
#pragma unroll
        for (int i = 0; i < 4; i++) {
            int n = i * 64 + rs;
            int gk = kb + ((cs ^ (n & 7)) << 3);
            gload_lds16(Wt + (size_t)n * KT + gk, sB + i * 4096 + wid * 512);
        }
        __syncthreads();
#pragma unroll
        for (int ks = 0; ks < 64; ks += 32) {
            short8 a[4], b[4];
            int q = (ks >> 3) + quad;
#pragma unroll
            for (int mt = 0; mt < 4; mt++) {
                int r = wm * 64 + mt * 16 + l16;
                a[mt] = *reinterpret_cast<const short8*>(
                    sA + r * 64 + ((q ^ (l16 & 7)) << 3));
            }
#pragma unroll
            for (int nt = 0; nt < 4; nt++) {
                int n = n_base + nt * 16 + l16;
                b[nt] = *reinterpret_cast<const short8*>(
                    sB + n * 64 + ((q ^ (l16 & 7)) << 3));
            }
#pragma unroll
            for (int mt = 0; mt < 4; mt++)
#pragma unroll
                for (int nt = 0; nt < 4; nt++)
                    acc[mt][nt] = __builtin_amdgcn_mfma_f32_16x16x32_bf16(a[mt], b[nt], acc[mt][nt], 0, 0, 0);
        }
    }
}

// layer 1: h = relu([agg1|xb] @ Wt1 + b1) -> Acat[:,256:512) (bf16)
__global__ __launch_bounds__(512) void k_gemm1(const unsigned short* __restrict__ agg1,
                                               const unsigned short* __restrict__ xb,
                                               const unsigned short* __restrict__ Wt1,
                                               const void* __restrict__ bias,
                                               const int* __restrict__ flag,
                                               unsigned short* __restrict__ acat_ws) {
    __shared__ unsigned short sA[8192];
    __shared__ unsigned short sB[16384];
    int f32 = flag[1];
    int wid = threadIdx.x >> 6, lane = threadIdx.x & 63;
    int wm = wid & 1, wn = wid >> 1;
    int quad = lane >> 4, l16 = lane & 15;
    int m_base = blockIdx.x * 128;
    floatx4 acc[4][4] = {};
    gemm_core_lds<256, 128, 128, 128>(agg1, xb, Wt1, acc, sA, sB, m_base);
#pragma unroll
    for (int nt = 0; nt < 4; nt++) {
        int n = wn * 64 + nt * 16 + l16;
        float bv = loadf(bias, n, f32);
#pragma unroll
        for (int mt = 0; mt < 4; mt++) {
#pragma unroll
            for (int r = 0; r < 4; r++) {
                int m = m_base + wm * 64 + mt * 16 + quad * 4 + r;
                if (m < Nn) {
                    float v = acc[mt][nt][r] + bv;
                    v = v > 0.f ? v : 0.f;
                    acat_ws[(size_t)m * 512 + 256 + n] = f2bf(v);
                }
            }
        }
    }
}

// layer 2: out = [agg2|h] @ Wt2 + b2
__global__ __launch_bounds__(512) void k_gemm2(const unsigned short* __restrict__ Wt2,
                                               const void* __restrict__ bias,
                                               const int* __restrict__ flag,
                                               const unsigned short* __restrict__ acat_ws,
                                               void* __restrict__ out) {
    __shared__ unsigned short sA[8192];
    __shared__ unsigned short sB[16384];
    int f32 = flag[1];
    int wid = threadIdx.x >> 6, lane = threadIdx.x & 63;
    int wm = wid & 1, wn = wid >> 1;
    int quad = lane >> 4, l16 = lane & 15;
    int m_base = blockIdx.x * 128;
    floatx4 acc[4][4] = {};
    gemm_core_lds<512, 256, 512, 512>(acat_ws, acat_ws + 256, Wt2, acc, sA, sB, m_base);
    __syncthreads();
#pragma unroll
    for (int nt = 0; nt < 4; nt++) {
        int n = wn * 64 + nt * 16 + l16;
        float bv = loadf(bias, n, f32);
#pragma unroll
        for (int mt = 0; mt < 4; mt++) {
#pragma unroll
            for (int r = 0; r < 4; r++) {
                int m = m_base + wm * 64 + mt * 16 + quad * 4 + r;
                if (m < Nn) {
                    float v = acc[mt][nt][r] + bv;
                    if (f32) ((float*)out)[(size_t)m * Hd + n] = v;
                    else     ((unsigned short*)out)[(size_t)m * Hd + n] = f2bf(v);
                }
            }
        }
    }
}

extern "C" void kernel_launch(void* const* d_in, const int* in_sizes, int n_in,
                              void* d_out, int out_size, void* d_ws, size_t ws_size,
                              hipStream_t stream) {
    const void* x   = d_in[0];
    const int*  ei  = (const int*)d_in[1];
    const void* Wl1 = d_in[2];
    const void* Wr1 = d_in[3];
    const void* b1  = d_in[4];
    const void* Wl2 = d_in[5];
    const void* Wr2 = d_in[6];
    const void* b2  = d_in[7];

    char* ws = (char*)d_ws;
    size_t off_cnt    = 0;
    size_t off_cur    = off_cnt + (size_t)Nn * 4;
    size_t off_rowptr = off_cur + (size_t)Nn * 4;
    size_t off_srcl   = off_rowptr + (size_t)(Nn + 4) * 4;
    size_t off_flag   = off_srcl + (size_t)Ee * 4;
    size_t off_bsum   = ((off_flag + 8 + 255) / 256) * 256;   // NB ints
    size_t off_bpre   = off_bsum + 128 * 4;                   // NB ints
    size_t off_wt1    = off_bpre + 128 * 4;
    size_t off_wt2    = off_wt1 + 256 * 256 * 2;
    size_t off_xb     = off_wt2 + 256 * 512 * 2;
    size_t off_agg1   = off_xb + (size_t)Nn * Fin * 2;
    size_t off_acat   = off_agg1 + (size_t)Nn * Fin * 2;

    int*            cnt     = (int*)(ws + off_cnt);
    int*            cur     = (int*)(ws + off_cur);
    int*            rowptr  = (int*)(ws + off_rowptr);
    int*            srcl    = (int*)(ws + off_srcl);
    int*            flag    = (int*)(ws + off_flag);
    int*            bsum    = (int*)(ws + off_bsum);
    int*            bpre    = (int*)(ws + off_bpre);
    unsigned short* Wt1     = (unsigned short*)(ws + off_wt1);
    unsigned short* Wt2     = (unsigned short*)(ws + off_wt2);
    unsigned short* xb      = (unsigned short*)(ws + off_xb);
    unsigned short* agg1    = (unsigned short*)(ws + off_agg1);
    unsigned short* acat_ws = (unsigned short*)(ws + off_acat);

    k_detect<<<1, 64, 0, stream>>>((const unsigned int*)ei, (const unsigned short*)x, flag);
    k_zero<<<(2 * Nn + 255) / 256, 256, 0, stream>>>(cnt, 2 * Nn);
    k_convert<<<(Nn * Fin / 4 + 255) / 256, 256, 0, stream>>>(x, xb, flag);
    k_prep<<<768, 256, 0, stream>>>(Wl1, Wr1, Wl2, Wr2, Wt1, Wt2, flag);

    int eb = (Ee + 255) / 256;
    k_count<<<eb, 256, 0, stream>>>(ei, flag, cnt);
    k_bsum<<<NB, 256, 0, stream>>>(cnt, bsum);
    k_bscan<<<1, 128, 0, stream>>>(bsum, bpre, rowptr);
    k_rowptr<<<NB, 256, 0, stream>>>(cnt, bpre, rowptr);
    k_fill<<<eb, 256, 0, stream>>>(ei, flag, rowptr, cur, srcl);

    int ab = (Nn * 64 + 255) / 256;
    int gx = (Nn + 127) / 128;

    k_agg1<<<ab, 256, 0, stream>>>(xb, agg1, rowptr, srcl);
    k_gemm1<<<gx, 512, 0, stream>>>(agg1, xb, Wt1, b1, flag, acat_ws);
    k_agg2<<<ab, 256, 0, stream>>>(rowptr, srcl, acat_ws);
    k_gemm2<<<gx, 512, 0, stream>>>(Wt2, b2, flag, acat_ws, d_out);
}

// Round 5
// 382.382 us; speedup vs baseline: 1.1128x; 1.1051x over previous
//
#include <hip/hip_runtime.h>

#define Nn 100000
#define Ee 600000
#define Fin 128
#define Hd  256
#define NB  ((Nn + 1023) / 1024)   // 98 scan blocks

typedef __attribute__((ext_vector_type(8))) short short8;
typedef __attribute__((ext_vector_type(4))) float floatx4;

__device__ __forceinline__ float bf2f(unsigned short h) {
    return __uint_as_float(((unsigned int)h) << 16);
}
__device__ __forceinline__ unsigned short f2bf(float f) {
    unsigned int u = __float_as_uint(f);
    u += 0x7FFFu + ((u >> 16) & 1u);   // round-to-nearest-even
    return (unsigned short)(u >> 16);
}
__device__ __forceinline__ float loadf(const void* p, int i, int f32) {
    return f32 ? ((const float*)p)[i] : bf2f(((const unsigned short*)p)[i]);
}
__device__ __forceinline__ void gload_lds16(const void* g, void* lds) {
    __builtin_amdgcn_global_load_lds((const __attribute__((address_space(1))) void*)g,
                                     (__attribute__((address_space(3))) void*)lds,
                                     16, 0, 0);
}

// ---- runtime probes: flag[0] = edge_index is int64, flag[1] = floats are f32 ----
__global__ void k_detect(const unsigned int* __restrict__ ei,
                         const unsigned short* __restrict__ xu,
                         int* __restrict__ flag) {
    if (blockIdx.x == 0 && threadIdx.x == 0) {
        int is64 = 1;
        for (int i = 1; i < 64; i += 2)
            if (ei[i] != 0u) { is64 = 0; break; }
        flag[0] = is64;
        int isf32 = 0;
        for (int i = 0; i < 512; i += 2) {
            unsigned e = (xu[i] >> 7) & 0xFFu;
            if (e >= 0xC0u) { isf32 = 1; break; }
        }
        flag[1] = isf32;
    }
}

__device__ __forceinline__ void get_edge(const int* __restrict__ ei, int is64, int e,
                                         int& s, int& d) {
    if (is64) { s = ei[2 * e]; d = ei[2 * (Ee + e)]; }
    else      { s = ei[e];     d = ei[Ee + e]; }
}

__global__ void k_zero(int* __restrict__ p, int n) {
    int i = blockIdx.x * 256 + threadIdx.x;
    if (i < n) p[i] = 0;
}

// ---- x -> xb (bf16 internal) ----
__global__ void k_convert(const void* __restrict__ x, unsigned short* __restrict__ xb,
                          const int* __restrict__ flag) {
    int i = (blockIdx.x * 256 + threadIdx.x) * 4;
    if (i >= Nn * Fin) return;
    if (flag[1]) {
        float4 v = ((const float4*)x)[i >> 2];
        ushort4 u;
        u.x = f2bf(v.x); u.y = f2bf(v.y); u.z = f2bf(v.z); u.w = f2bf(v.w);
        ((ushort4*)xb)[i >> 2] = u;
    } else {
        ((ushort4*)xb)[i >> 2] = ((const ushort4*)x)[i >> 2];
    }
}

// ---- weight pre-transpose: Wt[n][k] bf16, concat [Wl;Wr] along k ----
__global__ void k_prep(const void* __restrict__ Wl1, const void* __restrict__ Wr1,
                       const void* __restrict__ Wl2, const void* __restrict__ Wr2,
                       unsigned short* __restrict__ Wt1, unsigned short* __restrict__ Wt2,
                       const int* __restrict__ flag) {
    int f32 = flag[1];
    int tid = blockIdx.x * 256 + threadIdx.x;
    if (tid < 256 * 256) {
        int n = tid >> 8, k = tid & 255;
        float v = (k < 128) ? loadf(Wl1, k * 256 + n, f32) : loadf(Wr1, (k - 128) * 256 + n, f32);
        Wt1[n * 256 + k] = f2bf(v);
    }
    int t2 = tid - 256 * 256;
    if (t2 >= 0 && t2 < 256 * 512) {
        int n = t2 >> 9, k = t2 & 511;
        float v = (k < 256) ? loadf(Wl2, k * 256 + n, f32) : loadf(Wr2, (k - 256) * 256 + n, f32);
        Wt2[n * 512 + k] = f2bf(v);
    }
}

// ---- CSR build ----
__global__ void k_count(const int* __restrict__ ei, const int* __restrict__ flag,
                        int* __restrict__ cnt) {
    int e = blockIdx.x * 256 + threadIdx.x;
    if (e >= Ee) return;
    int is64 = flag[0], s, d;
    get_edge(ei, is64, e, s, d);
    atomicAdd(&cnt[d], 1);
}

// hierarchical scan: k_bsum -> k_bscan -> k_rowptr (all coalesced int4)
__global__ void k_bsum(const int* __restrict__ cnt, int* __restrict__ bsum) {
    __shared__ int red[256];
    int b = blockIdx.x, t = threadIdx.x;
    int i = b * 1024 + t * 4;
    int s = 0;
    if (i + 3 < Nn) {
        int4 v = *reinterpret_cast<const int4*>(cnt + i);
        s = v.x + v.y + v.z + v.w;
    } else {
        for (int j = 0; j < 4; j++) if (i + j < Nn) s += cnt[i + j];
    }
    red[t] = s;
    __syncthreads();
    for (int off = 128; off > 0; off >>= 1) {
        if (t < off) red[t] += red[t + off];
        __syncthreads();
    }
    if (t == 0) bsum[b] = red[0];
}

__global__ void k_bscan(const int* __restrict__ bsum, int* __restrict__ bpre,
                        int* __restrict__ rowptr) {
    __shared__ int sc[128];
    int t = threadIdx.x;
    int v = (t < NB) ? bsum[t] : 0;
    sc[t] = v;
    __syncthreads();
    for (int off = 1; off < 128; off <<= 1) {
        int add = (t >= off) ? sc[t - off] : 0;
        __syncthreads();
        sc[t] += add;
        __syncthreads();
    }
    if (t < NB) bpre[t] = sc[t] - v;          // exclusive prefix
    if (t == 127) rowptr[Nn] = sc[127];       // grand total (== Ee)
}

__global__ void k_rowptr(const int* __restrict__ cnt, const int* __restrict__ bpre,
                         int* __restrict__ rowptr) {
    __shared__ int sc[256];
    int b = blockIdx.x, t = threadIdx.x;
    int i = b * 1024 + t * 4;
    int4 c = make_int4(0, 0, 0, 0);
    if (i + 3 < Nn) {
        c = *reinterpret_cast<const int4*>(cnt + i);
    } else {
        if (i     < Nn) c.x = cnt[i];
        if (i + 1 < Nn) c.y = cnt[i + 1];
        if (i + 2 < Nn) c.z = cnt[i + 2];
        if (i + 3 < Nn) c.w = cnt[i + 3];
    }
    int s = c.x + c.y + c.z + c.w;
    sc[t] = s;
    __syncthreads();
    for (int off = 1; off < 256; off <<= 1) {
        int add = (t >= off) ? sc[t - off] : 0;
        __syncthreads();
        sc[t] += add;
        __syncthreads();
    }
    int p = bpre[b] + sc[t] - s;   // exclusive prefix of element i
    int4 r;
    r.x = p;
    r.y = r.x + c.x;
    r.z = r.y + c.y;
    r.w = r.z + c.z;
    if (i + 3 < Nn) {
        *reinterpret_cast<int4*>(rowptr + i) = r;
    } else {
        if (i     < Nn) rowptr[i]     = r.x;
        if (i + 1 < Nn) rowptr[i + 1] = r.y;
        if (i + 2 < Nn) rowptr[i + 2] = r.z;
        if (i + 3 < Nn) rowptr[i + 3] = r.w;
    }
}

__global__ void k_fill(const int* __restrict__ ei, const int* __restrict__ flag,
                       const int* __restrict__ rowptr, int* __restrict__ cur,
                       int* __restrict__ srcl) {
    int e = blockIdx.x * 256 + threadIdx.x;
    if (e >= Ee) return;
    int is64 = flag[0], s, d;
    get_edge(ei, is64, e, s, d);
    int pos = atomicAdd(&cur[d], 1);
    srcl[rowptr[d] + pos] = s;
}

// ---- gather-based mean aggregation: one wave per node, 8-deep MLP ----
template <int F, int SIN, int SOUT>
__device__ __forceinline__ void agg_body(const unsigned short* __restrict__ X,
                                         unsigned short* __restrict__ O,
                                         const int* __restrict__ rowptr,
                                         const int* __restrict__ srcl) {
    int gw = (blockIdx.x * blockDim.x + threadIdx.x) >> 6;
    int lane = threadIdx.x & 63;
    if (gw >= Nn) return;
    int b = rowptr[gw], e = rowptr[gw + 1];
    constexpr int C = F / 64;
    float acc[C] = {};
    if (e > b) {
        int last = e - 1;
        for (int i = b; i < e; i += 8) {
            int sv[8];
            float w[8];
#pragma unroll
            for (int j = 0; j < 8; j++) {
                int id = i + j;
                sv[j] = srcl[id < last ? id : last];
                w[j] = (id < e) ? 1.f : 0.f;
            }
            if constexpr (C == 2) {
                ushort2 u[8];
#pragma unroll
                for (int j = 0; j < 8; j++)
                    u[j] = *reinterpret_cast<const ushort2*>(X + (size_t)sv[j] * SIN + lane * 2);
#pragma unroll
                for (int j = 0; j < 8; j++) {
                    acc[0] = fmaf(w[j], bf2f(u[j].x), acc[0]);
                    acc[1] = fmaf(w[j], bf2f(u[j].y), acc[1]);
                }
            } else {
                ushort4 u[8];
#pragma unroll
                for (int j = 0; j < 8; j++)
                    u[j] = *reinterpret_cast<const ushort4*>(X + (size_t)sv[j] * SIN + lane * 4);
#pragma unroll
                for (int j = 0; j < 8; j++) {
                    acc[0] = fmaf(w[j], bf2f(u[j].x), acc[0]);
                    acc[1] = fmaf(w[j], bf2f(u[j].y), acc[1]);
                    acc[2] = fmaf(w[j], bf2f(u[j].z), acc[2]);
                    acc[3] = fmaf(w[j], bf2f(u[j].w), acc[3]);
                }
            }
        }
    }
    float inv = 1.f / (float)max(e - b, 1);
    unsigned short* op = O + (size_t)gw * SOUT + lane * C;
    if constexpr (C == 2) {
        ushort2 u; u.x = f2bf(acc[0] * inv); u.y = f2bf(acc[1] * inv);
        *reinterpret_cast<ushort2*>(op) = u;
    } else {
        ushort4 u;
        u.x = f2bf(acc[0] * inv); u.y = f2bf(acc[1] * inv);
        u.z = f2bf(acc[2] * inv); u.w = f2bf(acc[3] * inv);
        *reinterpret_cast<ushort4*>(op) = u;
    }
}

__global__ void k_agg1(const unsigned short* __restrict__ xb, unsigned short* __restrict__ agg1,
                       const int* __restrict__ rowptr, const int* __restrict__ srcl) {
    agg_body<Fin, Fin, Fin>(xb, agg1, rowptr, srcl);
}

__global__ void k_agg2(const int* __restrict__ rowptr, const int* __restrict__ srcl,
                       unsigned short* __restrict__ acat_ws) {
    agg_body<Hd, 512, 512>(acat_ws + 256, acat_ws, rowptr, srcl);
}

// ---- MFMA GEMM core: async LDS staging of A and B, BK=64, single-buffered ----
template <int KT, int K1, int S1, int S2>
__device__ __forceinline__ void gemm_core_lds(const unsigned short* __restrict__ A1,
                                              const unsigned short* __restrict__ A2,
                                              const unsigned short* __restrict__ Wt,
                                              floatx4 (&acc)[4][4],
                                              unsigned short* sA, unsigned short* sB,
                                              int m_base) {
    const int tid = threadIdx.x;
    const int lane = tid & 63, wid = tid >> 6;
    const int wm = wid & 1, wn = wid >> 1;
    const int quad = lane >> 4, l16 = lane & 15;
    const int n_base = wn * 64;
    const int rs = tid >> 3;       // row-octet owner: 64 rows per 512-thread pass
    const int cs = tid & 7;        // k-chunk slot (8 shorts each)

    for (int kb = 0; kb < KT; kb += 64) {
        __syncthreads();
        // stage A: 128 rows x 64 k, pre-swizzled global source -> linear LDS dest
#pragma unroll
        for (int i = 0; i < 2; i++) {
            int r = i * 64 + rs;
            int gk = kb + ((cs ^ (r & 7)) << 3);
            int m = m_base + r; if (m >= Nn) m = Nn - 1;
            const unsigned short* gp = (gk < K1)
                ? A1 + (size_t)m * S1 + gk
                : A2 + (size_t)m * S2 + (gk - K1);
            gload_lds16(gp, sA + i * 4096 + wid * 512);
        }
        // stage B: 256 rows x 64 k, same swizzle scheme
#pragma unroll
        for (int i = 0; i < 4; i++) {
            int n = i * 64 + rs;
            int gk = kb + ((cs ^ (n & 7)) << 3);
            gload_lds16(Wt + (size_t)n * KT + gk, sB + i * 4096 + wid * 512);
        }
        __syncthreads();
#pragma unroll
        for (int ks = 0; ks < 64; ks += 32) {
            short8 a[4], b[4];
            int q = (ks >> 3) + quad;
#pragma unroll
            for (int mt = 0; mt < 4; mt++) {
                int r = wm * 64 + mt * 16 + l16;
                a[mt] = *reinterpret_cast<const short8*>(
                    sA + r * 64 + ((q ^ (l16 & 7)) << 3));
            }
#pragma unroll
            for (int nt = 0; nt < 4; nt++) {
                int n = n_base + nt * 16 + l16;
                b[nt] = *reinterpret_cast<const short8*>(
                    sB + n * 64 + ((q ^ (l16 & 7)) << 3));
            }
#pragma unroll
            for (int mt = 0; mt < 4; mt++)
#pragma unroll
                for (int nt = 0; nt < 4; nt++)
                    acc[mt][nt] = __builtin_amdgcn_mfma_f32_16x16x32_bf16(a[mt], b[nt], acc[mt][nt], 0, 0, 0);
        }
    }
}

// layer 1: h = relu([agg1|xb] @ Wt1 + b1) -> Acat[:,256:512) (bf16)
// Coalesced epilogue: fragments -> LDS bounce (64 rows x 256 bf16 = 32 KB in sB)
// -> contiguous 512 B row stores (16 B/lane). Replaces 2-byte scattered stores
// (32 B row-segments, partial-line write amplification).
__global__ __launch_bounds__(512) void k_gemm1(const unsigned short* __restrict__ agg1,
                                               const unsigned short* __restrict__ xb,
                                               const unsigned short* __restrict__ Wt1,
                                               const void* __restrict__ bias,
                                               const int* __restrict__ flag,
                                               unsigned short* __restrict__ acat_ws) {
    __shared__ unsigned short sA[8192];
    __shared__ unsigned short sB[16384];
    int f32 = flag[1];
    int tid = threadIdx.x;
    int wid = tid >> 6, lane = tid & 63;
    int wm = wid & 1, wn = wid >> 1;
    int quad = lane >> 4, l16 = lane & 15;
    int m_base = blockIdx.x * 128;
    floatx4 acc[4][4] = {};
    gemm_core_lds<256, 128, 128, 128>(agg1, xb, Wt1, acc, sA, sB, m_base);
#pragma unroll
    for (int p = 0; p < 2; p++) {
        __syncthreads();                       // sB free (K-loop / prev pass done)
        if (wm == p) {
#pragma unroll
            for (int nt = 0; nt < 4; nt++) {
                int n = wn * 64 + nt * 16 + l16;
                float bv = loadf(bias, n, f32);
#pragma unroll
                for (int mt = 0; mt < 4; mt++) {
#pragma unroll
                    for (int r = 0; r < 4; r++) {
                        float v = acc[mt][nt][r] + bv;
                        v = v > 0.f ? v : 0.f;
                        sB[(mt * 16 + quad * 4 + r) * 256 + n] = f2bf(v);
                    }
                }
            }
        }
        __syncthreads();
#pragma unroll
        for (int rnd = 0; rnd < 4; rnd++) {
            int rl = rnd * 16 + (tid >> 5);
            int m = m_base + p * 64 + rl;
            if (m < Nn)
                *reinterpret_cast<short8*>(acat_ws + (size_t)m * 512 + 256 + (tid & 31) * 8) =
                    *reinterpret_cast<const short8*>(sB + rl * 256 + (tid & 31) * 8);
        }
    }
}

// layer 2: out = [agg2|h] @ Wt2 + b2
// Coalesced epilogue: 4 passes of 32 rows x 256 f32 (32 KB) through sB,
// then contiguous 1 KB row stores (f32) or 512 B (bf16).
__global__ __launch_bounds__(512) void k_gemm2(const unsigned short* __restrict__ Wt2,
                                               const void* __restrict__ bias,
                                               const int* __restrict__ flag,
                                               const unsigned short* __restrict__ acat_ws,
                                               void* __restrict__ out) {
    __shared__ unsigned short sA[8192];
    __shared__ unsigned short sB[16384];
    int f32 = flag[1];
    int tid = threadIdx.x;
    int wid = tid >> 6, lane = tid & 63;
    int wm = wid & 1, wn = wid >> 1;
    int quad = lane >> 4, l16 = lane & 15;
    int m_base = blockIdx.x * 128;
    floatx4 acc[4][4] = {};
    gemm_core_lds<512, 256, 512, 512>(acat_ws, acat_ws + 256, Wt2, acc, sA, sB, m_base);
    float* sF = (float*)sB;                    // 32 rows x 256 f32 = 32 KB
#pragma unroll
    for (int q = 0; q < 4; q++) {
        __syncthreads();
        if (wm == (q >> 1)) {
#pragma unroll
            for (int nt = 0; nt < 4; nt++) {
                int n = wn * 64 + nt * 16 + l16;
                float bv = loadf(bias, n, f32);
#pragma unroll
                for (int mt2 = 0; mt2 < 2; mt2++) {
                    int mt = (q & 1) * 2 + mt2;
#pragma unroll
                    for (int r = 0; r < 4; r++)
                        sF[(mt2 * 16 + quad * 4 + r) * 256 + n] = acc[mt][nt][r] + bv;
                }
            }
        }
        __syncthreads();
#pragma unroll
        for (int rnd = 0; rnd < 2; rnd++) {
            int rl = rnd * 16 + (tid >> 5);
            int m = m_base + q * 32 + rl;
            if (m < Nn) {
                if (f32) {
                    float4* dst = (float4*)((float*)out + (size_t)m * 256) + (tid & 31) * 2;
                    const float4* src = (const float4*)(sF + rl * 256) + (tid & 31) * 2;
                    dst[0] = src[0];
                    dst[1] = src[1];
                } else {
                    const float* src = sF + rl * 256 + (tid & 31) * 8;
                    short8 pk;
#pragma unroll
                    for (int j = 0; j < 8; j++)
                        ((unsigned short*)&pk)[j] = f2bf(src[j]);
                    *reinterpret_cast<short8*>((unsigned short*)out + (size_t)m * 256 + (tid & 31) * 8) = pk;
                }
            }
        }
    }
}

extern "C" void kernel_launch(void* const* d_in, const int* in_sizes, int n_in,
                              void* d_out, int out_size, void* d_ws, size_t ws_size,
                              hipStream_t stream) {
    const void* x   = d_in[0];
    const int*  ei  = (const int*)d_in[1];
    const void* Wl1 = d_in[2];
    const void* Wr1 = d_in[3];
    const void* b1  = d_in[4];
    const void* Wl2 = d_in[5];
    const void* Wr2 = d_in[6];
    const void* b2  = d_in[7];

    char* ws = (char*)d_ws;
    size_t off_cnt    = 0;
    size_t off_cur    = off_cnt + (size_t)Nn * 4;
    size_t off_rowptr = off_cur + (size_t)Nn * 4;
    size_t off_srcl   = off_rowptr + (size_t)(Nn + 4) * 4;
    size_t off_flag   = off_srcl + (size_t)Ee * 4;
    size_t off_bsum   = ((off_flag + 8 + 255) / 256) * 256;   // NB ints
    size_t off_bpre   = off_bsum + 128 * 4;                   // NB ints
    size_t off_wt1    = off_bpre + 128 * 4;
    size_t off_wt2    = off_wt1 + 256 * 256 * 2;
    size_t off_xb     = off_wt2 + 256 * 512 * 2;
    size_t off_agg1   = off_xb + (size_t)Nn * Fin * 2;
    size_t off_acat   = off_agg1 + (size_t)Nn * Fin * 2;

    int*            cnt     = (int*)(ws + off_cnt);
    int*            cur     = (int*)(ws + off_cur);
    int*            rowptr  = (int*)(ws + off_rowptr);
    int*            srcl    = (int*)(ws + off_srcl);
    int*            flag    = (int*)(ws + off_flag);
    int*            bsum    = (int*)(ws + off_bsum);
    int*            bpre    = (int*)(ws + off_bpre);
    unsigned short* Wt1     = (unsigned short*)(ws + off_wt1);
    unsigned short* Wt2     = (unsigned short*)(ws + off_wt2);
    unsigned short* xb      = (unsigned short*)(ws + off_xb);
    unsigned short* agg1    = (unsigned short*)(ws + off_agg1);
    unsigned short* acat_ws = (unsigned short*)(ws + off_acat);

    k_detect<<<1, 64, 0, stream>>>((const unsigned int*)ei, (const unsigned short*)x, flag);
    k_zero<<<(2 * Nn + 255) / 256, 256, 0, stream>>>(cnt, 2 * Nn);
    k_convert<<<(Nn * Fin / 4 + 255) / 256, 256, 0, stream>>>(x, xb, flag);
    k_prep<<<768, 256, 0, stream>>>(Wl1, Wr1, Wl2, Wr2, Wt1, Wt2, flag);

    int eb = (Ee + 255) / 256;
    k_count<<<eb, 256, 0, stream>>>(ei, flag, cnt);
    k_bsum<<<NB, 256, 0, stream>>>(cnt, bsum);
    k_bscan<<<1, 128, 0, stream>>>(bsum, bpre, rowptr);
    k_rowptr<<<NB, 256, 0, stream>>>(cnt, bpre, rowptr);
    k_fill<<<eb, 256, 0, stream>>>(ei, flag, rowptr, cur, srcl);

    int ab = (Nn * 64 + 255) / 256;
    int gx = (Nn + 127) / 128;

    k_agg1<<<ab, 256, 0, stream>>>(xb, agg1, rowptr, srcl);
    k_gemm1<<<gx, 512, 0, stream>>>(agg1, xb, Wt1, b1, flag, acat_ws);
    k_agg2<<<ab, 256, 0, stream>>>(rowptr, srcl, acat_ws);
    k_gemm2<<<gx, 512, 0, stream>>>(Wt2, b2, flag, acat_ws, d_out);
}

// Round 7
// 379.046 us; speedup vs baseline: 1.1226x; 1.0088x over previous
//
#include <hip/hip_runtime.h>

#define Nn 100000
#define Ee 600000
#define Fin 128
#define Hd  256
#define NB  ((Nn + 1023) / 1024)   // 98 scan blocks
#define CB  12500                  // convert blocks: Nn*Fin/4/256
#define PB  768                    // prep blocks
#define EB  ((Ee + 255) / 256)     // edge blocks

typedef __attribute__((ext_vector_type(8))) short short8;
typedef __attribute__((ext_vector_type(4))) float floatx4;

__device__ __forceinline__ float bf2f(unsigned short h) {
    return __uint_as_float(((unsigned int)h) << 16);
}
__device__ __forceinline__ unsigned short f2bf(float f) {
    unsigned int u = __float_as_uint(f);
    u += 0x7FFFu + ((u >> 16) & 1u);   // round-to-nearest-even
    return (unsigned short)(u >> 16);
}
__device__ __forceinline__ float loadf(const void* p, int i, int f32) {
    return f32 ? ((const float*)p)[i] : bf2f(((const unsigned short*)p)[i]);
}
__device__ __forceinline__ void gload_lds16(const void* g, void* lds) {
    __builtin_amdgcn_global_load_lds((const __attribute__((address_space(1))) void*)g,
                                     (__attribute__((address_space(3))) void*)lds,
                                     16, 0, 0);
}

__device__ __forceinline__ void get_edge(const int* __restrict__ ei, int is64, int e,
                                         int& s, int& d) {
    if (is64) { s = ei[2 * e]; d = ei[2 * (Ee + e)]; }
    else      { s = ei[e];     d = ei[Ee + e]; }
}

// ---- fused: runtime probes + cnt/cur zero ----
__global__ void k_init(const unsigned int* __restrict__ ei,
                       const unsigned short* __restrict__ xu,
                       int* __restrict__ flag, int* __restrict__ cnt) {
    int i = blockIdx.x * 256 + threadIdx.x;
    if (i < 2 * Nn) cnt[i] = 0;            // cnt and cur are contiguous
    if (blockIdx.x == 0 && threadIdx.x == 0) {
        int is64 = 1;
        for (int k = 1; k < 64; k += 2)
            if (ei[k] != 0u) { is64 = 0; break; }
        flag[0] = is64;
        int isf32 = 0;
        for (int k = 0; k < 512; k += 2) {
            unsigned e = (xu[k] >> 7) & 0xFFu;
            if (e >= 0xC0u) { isf32 = 1; break; }
        }
        flag[1] = isf32;
    }
}

// ---- fused: x->xb convert | weight pre-transpose | edge degree count ----
__global__ void k_pre(const void* __restrict__ x, unsigned short* __restrict__ xb,
                      const void* __restrict__ Wl1, const void* __restrict__ Wr1,
                      const void* __restrict__ Wl2, const void* __restrict__ Wr2,
                      unsigned short* __restrict__ Wt1, unsigned short* __restrict__ Wt2,
                      const int* __restrict__ ei, int* __restrict__ cnt,
                      const int* __restrict__ flag) {
    int bid = blockIdx.x;
    if (bid < CB) {
        int i = (bid * 256 + threadIdx.x) * 4;
        if (i >= Nn * Fin) return;
        if (flag[1]) {
            float4 v = ((const float4*)x)[i >> 2];
            ushort4 u;
            u.x = f2bf(v.x); u.y = f2bf(v.y); u.z = f2bf(v.z); u.w = f2bf(v.w);
            ((ushort4*)xb)[i >> 2] = u;
        } else {
            ((ushort4*)xb)[i >> 2] = ((const ushort4*)x)[i >> 2];
        }
    } else if (bid < CB + PB) {
        int f32 = flag[1];
        int tid = (bid - CB) * 256 + threadIdx.x;
        if (tid < 256 * 256) {
            int n = tid >> 8, k = tid & 255;
            float v = (k < 128) ? loadf(Wl1, k * 256 + n, f32) : loadf(Wr1, (k - 128) * 256 + n, f32);
            Wt1[n * 256 + k] = f2bf(v);
        }
        int t2 = tid - 256 * 256;
        if (t2 >= 0 && t2 < 256 * 512) {
            int n = t2 >> 9, k = t2 & 511;
            float v = (k < 256) ? loadf(Wl2, k * 256 + n, f32) : loadf(Wr2, (k - 256) * 256 + n, f32);
            Wt2[n * 512 + k] = f2bf(v);
        }
    } else {
        int e = (bid - CB - PB) * 256 + threadIdx.x;
        if (e >= Ee) return;
        int is64 = flag[0], s, d;
        get_edge(ei, is64, e, s, d);
        atomicAdd(&cnt[d], 1);
    }
}

// hierarchical scan: k_bsum -> k_bscan -> k_rowptr (all coalesced int4)
__global__ void k_bsum(const int* __restrict__ cnt, int* __restrict__ bsum) {
    __shared__ int red[256];
    int b = blockIdx.x, t = threadIdx.x;
    int i = b * 1024 + t * 4;
    int s = 0;
    if (i + 3 < Nn) {
        int4 v = *reinterpret_cast<const int4*>(cnt + i);
        s = v.x + v.y + v.z + v.w;
    } else {
        for (int j = 0; j < 4; j++) if (i + j < Nn) s += cnt[i + j];
    }
    red[t] = s;
    __syncthreads();
    for (int off = 128; off > 0; off >>= 1) {
        if (t < off) red[t] += red[t + off];
        __syncthreads();
    }
    if (t == 0) bsum[b] = red[0];
}

__global__ void k_bscan(const int* __restrict__ bsum, int* __restrict__ bpre,
                        int* __restrict__ rowptr) {
    __shared__ int sc[128];
    int t = threadIdx.x;
    int v = (t < NB) ? bsum[t] : 0;
    sc[t] = v;
    __syncthreads();
    for (int off = 1; off < 128; off <<= 1) {
        int add = (t >= off) ? sc[t - off] : 0;
        __syncthreads();
        sc[t] += add;
        __syncthreads();
    }
    if (t < NB) bpre[t] = sc[t] - v;          // exclusive prefix
    if (t == 127) rowptr[Nn] = sc[127];       // grand total (== Ee)
}

__global__ void k_rowptr(const int* __restrict__ cnt, const int* __restrict__ bpre,
                         int* __restrict__ rowptr) {
    __shared__ int sc[256];
    int b = blockIdx.x, t = threadIdx.x;
    int i = b * 1024 + t * 4;
    int4 c = make_int4(0, 0, 0, 0);
    if (i + 3 < Nn) {
        c = *reinterpret_cast<const int4*>(cnt + i);
    } else {
        if (i     < Nn) c.x = cnt[i];
        if (i + 1 < Nn) c.y = cnt[i + 1];
        if (i + 2 < Nn) c.z = cnt[i + 2];
        if (i + 3 < Nn) c.w = cnt[i + 3];
    }
    int s = c.x + c.y + c.z + c.w;
    sc[t] = s;
    __syncthreads();
    for (int off = 1; off < 256; off <<= 1) {
        int add = (t >= off) ? sc[t - off] : 0;
        __syncthreads();
        sc[t] += add;
        __syncthreads();
    }
    int p = bpre[b] + sc[t] - s;   // exclusive prefix of element i
    int4 r;
    r.x = p;
    r.y = r.x + c.x;
    r.z = r.y + c.y;
    r.w = r.z + c.z;
    if (i + 3 < Nn) {
        *reinterpret_cast<int4*>(rowptr + i) = r;
    } else {
        if (i     < Nn) rowptr[i]     = r.x;
        if (i + 1 < Nn) rowptr[i + 1] = r.y;
        if (i + 2 < Nn) rowptr[i + 2] = r.z;
        if (i + 3 < Nn) rowptr[i + 3] = r.w;
    }
}

__global__ void k_fill(const int* __restrict__ ei, const int* __restrict__ flag,
                       const int* __restrict__ rowptr, int* __restrict__ cur,
                       int* __restrict__ srcl) {
    int e = blockIdx.x * 256 + threadIdx.x;
    if (e >= Ee) return;
    int is64 = flag[0], s, d;
    get_edge(ei, is64, e, s, d);
    int pos = atomicAdd(&cur[d], 1);
    srcl[rowptr[d] + pos] = s;
}

// ---- gather-based mean aggregation: one wave per node, 8-deep MLP ----
template <int F, int SIN, int SOUT>
__device__ __forceinline__ void agg_body(const unsigned short* __restrict__ X,
                                         unsigned short* __restrict__ O,
                                         const int* __restrict__ rowptr,
                                         const int* __restrict__ srcl) {
    int gw = (blockIdx.x * blockDim.x + threadIdx.x) >> 6;
    int lane = threadIdx.x & 63;
    if (gw >= Nn) return;
    int b = rowptr[gw], e = rowptr[gw + 1];
    constexpr int C = F / 64;
    float acc[C] = {};
    if (e > b) {
        int last = e - 1;
        for (int i = b; i < e; i += 8) {
            int sv[8];
            float w[8];
#pragma unroll
            for (int j = 0; j < 8; j++) {
                int id = i + j;
                sv[j] = srcl[id < last ? id : last];
                w[j] = (id < e) ? 1.f : 0.f;
            }
            if constexpr (C == 2) {
                ushort2 u[8];
#pragma unroll
                for (int j = 0; j < 8; j++)
                    u[j] = *reinterpret_cast<const ushort2*>(X + (size_t)sv[j] * SIN + lane * 2);
#pragma unroll
                for (int j = 0; j < 8; j++) {
                    acc[0] = fmaf(w[j], bf2f(u[j].x), acc[0]);
                    acc[1] = fmaf(w[j], bf2f(u[j].y), acc[1]);
                }
            } else {
                ushort4 u[8];
#pragma unroll
                for (int j = 0; j < 8; j++)
                    u[j] = *reinterpret_cast<const ushort4*>(X + (size_t)sv[j] * SIN + lane * 4);
#pragma unroll
                for (int j = 0; j < 8; j++) {
                    acc[0] = fmaf(w[j], bf2f(u[j].x), acc[0]);
                    acc[1] = fmaf(w[j], bf2f(u[j].y), acc[1]);
                    acc[2] = fmaf(w[j], bf2f(u[j].z), acc[2]);
                    acc[3] = fmaf(w[j], bf2f(u[j].w), acc[3]);
                }
            }
        }
    }
    float inv = 1.f / (float)max(e - b, 1);
    unsigned short* op = O + (size_t)gw * SOUT + lane * C;
    if constexpr (C == 2) {
        ushort2 u; u.x = f2bf(acc[0] * inv); u.y = f2bf(acc[1] * inv);
        *reinterpret_cast<ushort2*>(op) = u;
    } else {
        ushort4 u;
        u.x = f2bf(acc[0] * inv); u.y = f2bf(acc[1] * inv);
        u.z = f2bf(acc[2] * inv); u.w = f2bf(acc[3] * inv);
        *reinterpret_cast<ushort4*>(op) = u;
    }
}

__global__ void k_agg1(const unsigned short* __restrict__ xb, unsigned short* __restrict__ agg1,
                       const int* __restrict__ rowptr, const int* __restrict__ srcl) {
    agg_body<Fin, Fin, Fin>(xb, agg1, rowptr, srcl);
}

__global__ void k_agg2(const int* __restrict__ rowptr, const int* __restrict__ srcl,
                       unsigned short* __restrict__ acat_ws) {
    agg_body<Hd, 512, 512>(acat_ws + 256, acat_ws, rowptr, srcl);
}

// ---- MFMA GEMM core: 2-phase prefetch pipeline, BK=32 double-buffered ----
// Schedule: STAGE(0); for t { __syncthreads(); STAGE(t+1 -> buf^1); COMPUTE(buf) }.
// ONE barrier per tile. The barrier's implicit vmcnt(0) drains only tile t's
// loads (issued one full COMPUTE earlier -> latency hidden); tile t+1's loads
// stay in flight across COMPUTE(t). STAGE(t+1) writes buf^1 whose last readers
// (COMPUTE t-1) finished ds_reads before this barrier -> safe.
// LDS = 2 x (8KB A + 16KB B) = 48 KB -> 3 blocks/CU preserved.
// Wave-uniform LDS dest (m104 contract): wave wid stages rows wid*16..+15,
// lane l -> row wid*16+(l>>2), chunk l&3, lands at (wid*512 + l*8) shorts.
// Swizzle for 32-k rows: chunk = cs ^ ((row>>1)&3); 2-way bank aliasing = free.
template <int KT, int K1, int S1, int S2>
__device__ __forceinline__ void gemm_core_pipe(const unsigned short* __restrict__ A1,
                                               const unsigned short* __restrict__ A2,
                                               const unsigned short* __restrict__ Wt,
                                               floatx4 (&acc)[4][4],
                                               unsigned short* sA, unsigned short* sB,
                                               int m_base) {
    const int tid = threadIdx.x;
    const int lane = tid & 63, wid = tid >> 6;
    const int wm = wid & 1, wn = wid >> 1;
    const int quad = lane >> 4, l16 = lane & 15;
    const int rs = tid >> 2;       // row 0..127
    const int cs = tid & 3;        // k-chunk slot (8 shorts)
    constexpr int NT = KT / 32;

#define STAGE(t, buf)                                                              \
    {                                                                              \
        int kb_ = (t) * 32;                                                        \
        {                                                                          \
            int gk_ = kb_ + ((cs ^ ((rs >> 1) & 3)) << 3);                         \
            int m_ = m_base + rs; if (m_ >= Nn) m_ = Nn - 1;                       \
            const unsigned short* gp_ = (gk_ < K1)                                 \
                ? A1 + (size_t)m_ * S1 + gk_                                       \
                : A2 + (size_t)m_ * S2 + (gk_ - K1);                               \
            gload_lds16(gp_, sA + (buf) * 4096 + wid * 512);                       \
        }                                                                          \
        _Pragma("unroll")                                                          \
        for (int i_ = 0; i_ < 2; i_++) {                                           \
            int n_ = i_ * 128 + rs;                                                \
            int gk_ = kb_ + ((cs ^ ((n_ >> 1) & 3)) << 3);                         \
            gload_lds16(Wt + (size_t)n_ * KT + gk_,                                \
                        sB + (buf) * 8192 + i_ * 4096 + wid * 512);                \
        }                                                                          \
    }

#define COMPUTE(buf)                                                               \
    {                                                                              \
        short8 a_[4], b_[4];                                                       \
        _Pragma("unroll")                                                          \
        for (int mt_ = 0; mt_ < 4; mt_++) {                                        \
            int r_ = wm * 64 + mt_ * 16 + l16;                                     \
            a_[mt_] = *reinterpret_cast<const short8*>(                            \
                sA + (buf) * 4096 + r_ * 32 + ((quad ^ ((r_ >> 1) & 3)) << 3));    \
        }                                                                          \
        _Pragma("unroll")                                                          \
        for (int nt_ = 0; nt_ < 4; nt_++) {                                        \
            int n_ = wn * 64 + nt_ * 16 + l16;                                     \
            b_[nt_] = *reinterpret_cast<const short8*>(                            \
                sB + (buf) * 8192 + n_ * 32 + ((quad ^ ((n_ >> 1) & 3)) << 3));    \
        }                                                                          \
        _Pragma("unroll")                                                          \
        for (int mt_ = 0; mt_ < 4; mt_++)                                          \
            _Pragma("unroll")                                                      \
            for (int nt_ = 0; nt_ < 4; nt_++)                                      \
                acc[mt_][nt_] = __builtin_amdgcn_mfma_f32_16x16x32_bf16(           \
                    a_[mt_], b_[nt_], acc[mt_][nt_], 0, 0, 0);                     \
    }

    STAGE(0, 0)
#pragma unroll
    for (int t = 0; t < NT; t++) {
        __syncthreads();                       // drains tile t's loads (overlapped with COMPUTE t-1)
        if (t + 1 < NT) STAGE(t + 1, (t + 1) & 1)
        COMPUTE(t & 1)
    }
#undef STAGE
#undef COMPUTE
}

// layer 1: h = relu([agg1|xb] @ Wt1 + b1) -> Acat[:,256:512) (bf16)
// Coalesced epilogue via 32 KB LDS bounce (sB reused).
__global__ __launch_bounds__(512) void k_gemm1(const unsigned short* __restrict__ agg1,
                                               const unsigned short* __restrict__ xb,
                                               const unsigned short* __restrict__ Wt1,
                                               const void* __restrict__ bias,
                                               const int* __restrict__ flag,
                                               unsigned short* __restrict__ acat_ws) {
    __shared__ unsigned short sA[8192];    // 2 x 8KB
    __shared__ unsigned short sB[16384];   // 2 x 16KB
    int f32 = flag[1];
    int tid = threadIdx.x;
    int wid = tid >> 6, lane = tid & 63;
    int wm = wid & 1, wn = wid >> 1;
    int quad = lane >> 4, l16 = lane & 15;
    int m_base = blockIdx.x * 128;
    floatx4 acc[4][4] = {};
    gemm_core_pipe<256, 128, 128, 128>(agg1, xb, Wt1, acc, sA, sB, m_base);
#pragma unroll
    for (int p = 0; p < 2; p++) {
        __syncthreads();                       // sB free (K-loop / prev pass done)
        if (wm == p) {
#pragma unroll
            for (int nt = 0; nt < 4; nt++) {
                int n = wn * 64 + nt * 16 + l16;
                float bv = loadf(bias, n, f32);
#pragma unroll
                for (int mt = 0; mt < 4; mt++) {
#pragma unroll
                    for (int r = 0; r < 4; r++) {
                        float v = acc[mt][nt][r] + bv;
                        v = v > 0.f ? v : 0.f;
                        sB[(mt * 16 + quad * 4 + r) * 256 + n] = f2bf(v);
                    }
                }
            }
        }
        __syncthreads();
#pragma unroll
        for (int rnd = 0; rnd < 4; rnd++) {
            int rl = rnd * 16 + (tid >> 5);
            int m = m_base + p * 64 + rl;
            if (m < Nn)
                *reinterpret_cast<short8*>(acat_ws + (size_t)m * 512 + 256 + (tid & 31) * 8) =
                    *reinterpret_cast<const short8*>(sB + rl * 256 + (tid & 31) * 8);
        }
    }
}

// layer 2: out = [agg2|h] @ Wt2 + b2. Acat row = [agg|h] contiguous 512-k
// stream, so K1=512 makes the A2 branch compile-time dead.
__global__ __launch_bounds__(512) void k_gemm2(const unsigned short* __restrict__ Wt2,
                                               const void* __restrict__ bias,
                                               const int* __restrict__ flag,
                                               const unsigned short* __restrict__ acat_ws,
                                               void* __restrict__ out) {
    __shared__ unsigned short sA[8192];
    __shared__ unsigned short sB[16384];
    int f32 = flag[1];
    int tid = threadIdx.x;
    int wid = tid >> 6, lane = tid & 63;
    int wm = wid & 1, wn = wid >> 1;
    int quad = lane >> 4, l16 = lane & 15;
    int m_base = blockIdx.x * 128;
    floatx4 acc[4][4] = {};
    gemm_core_pipe<512, 512, 512, 512>(acat_ws, acat_ws, Wt2, acc, sA, sB, m_base);
    float* sF = (float*)sB;                    // 32 rows x 256 f32 = 32 KB
#pragma unroll
    for (int q = 0; q < 4; q++) {
        __syncthreads();
        if (wm == (q >> 1)) {
#pragma unroll
            for (int nt = 0; nt < 4; nt++) {
                int n = wn * 64 + nt * 16 + l16;
                float bv = loadf(bias, n, f32);
#pragma unroll
                for (int mt2 = 0; mt2 < 2; mt2++) {
                    int mt = (q & 1) * 2 + mt2;
#pragma unroll
                    for (int r = 0; r < 4; r++)
                        sF[(mt2 * 16 + quad * 4 + r) * 256 + n] = acc[mt][nt][r] + bv;
                }
            }
        }
        __syncthreads();
#pragma unroll
        for (int rnd = 0; rnd < 2; rnd++) {
            int rl = rnd * 16 + (tid >> 5);
            int m = m_base + q * 32 + rl;
            if (m < Nn) {
                if (f32) {
                    float4* dst = (float4*)((float*)out + (size_t)m * 256) + (tid & 31) * 2;
                    const float4* src = (const float4*)(sF + rl * 256) + (tid & 31) * 2;
                    dst[0] = src[0];
                    dst[1] = src[1];
                } else {
                    const float* src = sF + rl * 256 + (tid & 31) * 8;
                    short8 pk;
#pragma unroll
                    for (int j = 0; j < 8; j++)
                        ((unsigned short*)&pk)[j] = f2bf(src[j]);
                    *reinterpret_cast<short8*>((unsigned short*)out + (size_t)m * 256 + (tid & 31) * 8) = pk;
                }
            }
        }
    }
}

extern "C" void kernel_launch(void* const* d_in, const int* in_sizes, int n_in,
                              void* d_out, int out_size, void* d_ws, size_t ws_size,
                              hipStream_t stream) {
    const void* x   = d_in[0];
    const int*  ei  = (const int*)d_in[1];
    const void* Wl1 = d_in[2];
    const void* Wr1 = d_in[3];
    const void* b1  = d_in[4];
    const void* Wl2 = d_in[5];
    const void* Wr2 = d_in[6];
    const void* b2  = d_in[7];

    char* ws = (char*)d_ws;
    size_t off_cnt    = 0;
    size_t off_cur    = off_cnt + (size_t)Nn * 4;
    size_t off_rowptr = off_cur + (size_t)Nn * 4;
    size_t off_srcl   = off_rowptr + (size_t)(Nn + 4) * 4;
    size_t off_flag   = off_srcl + (size_t)Ee * 4;
    size_t off_bsum   = ((off_flag + 8 + 255) / 256) * 256;   // NB ints
    size_t off_bpre   = off_bsum + 128 * 4;                   // NB ints
    size_t off_wt1    = off_bpre + 128 * 4;
    size_t off_wt2    = off_wt1 + 256 * 256 * 2;
    size_t off_xb     = off_wt2 + 256 * 512 * 2;
    size_t off_agg1   = off_xb + (size_t)Nn * Fin * 2;
    size_t off_acat   = off_agg1 + (size_t)Nn * Fin * 2;

    int*            cnt     = (int*)(ws + off_cnt);
    int*            cur     = (int*)(ws + off_cur);
    int*            rowptr  = (int*)(ws + off_rowptr);
    int*            srcl    = (int*)(ws + off_srcl);
    int*            flag    = (int*)(ws + off_flag);
    int*            bsum    = (int*)(ws + off_bsum);
    int*            bpre    = (int*)(ws + off_bpre);
    unsigned short* Wt1     = (unsigned short*)(ws + off_wt1);
    unsigned short* Wt2     = (unsigned short*)(ws + off_wt2);
    unsigned short* xb      = (unsigned short*)(ws + off_xb);
    unsigned short* agg1    = (unsigned short*)(ws + off_agg1);
    unsigned short* acat_ws = (unsigned short*)(ws + off_acat);

    k_init<<<(2 * Nn + 255) / 256, 256, 0, stream>>>((const unsigned int*)ei,
                                                     (const unsigned short*)x, flag, cnt);
    k_pre<<<CB + PB + EB, 256, 0, stream>>>(x, xb, Wl1, Wr1, Wl2, Wr2, Wt1, Wt2,
                                            ei, cnt, flag);
    k_bsum<<<NB, 256, 0, stream>>>(cnt, bsum);
    k_bscan<<<1, 128, 0, stream>>>(bsum, bpre, rowptr);
    k_rowptr<<<NB, 256, 0, stream>>>(cnt, bpre, rowptr);
    k_fill<<<EB, 256, 0, stream>>>(ei, flag, rowptr, cur, srcl);

    int ab = (Nn * 64 + 255) / 256;
    int gx = (Nn + 127) / 128;

    k_agg1<<<ab, 256, 0, stream>>>(xb, agg1, rowptr, srcl);
    k_gemm1<<<gx, 512, 0, stream>>>(agg1, xb, Wt1, b1, flag, acat_ws);
    k_agg2<<<ab, 256, 0, stream>>>(rowptr, srcl, acat_ws);
    k_gemm2<<<gx, 512, 0, stream>>>(Wt2, b2, flag, acat_ws, d_out);
}